// Round 1
// baseline (1124.434 us; speedup 1.0000x reference)
//
#include <hip/hip_runtime.h>
#include <math.h>

// Problem constants (B=64, T=512, D=1024 from reference setup)
constexpr int   NMc      = 5;
constexpr float TEMP_INV = 10.0f;     // 1/TEMP
constexpr float NEG_BIG  = -1e30f;
constexpr int   TM       = 4;         // t-values per block (== #waves)

__device__ inline float wave_reduce_sum(float v) {
#pragma unroll
    for (int off = 32; off; off >>= 1) v += __shfl_xor(v, off);
    return v;
}

__device__ inline float dot16(const float4 a0, const float4 a1, const float4 a2, const float4 a3,
                              const float4 x0, const float4 x1, const float4 x2, const float4 x3) {
    return a0.x*x0.x + a0.y*x0.y + a0.z*x0.z + a0.w*x0.w
         + a1.x*x1.x + a1.y*x1.y + a1.z*x1.z + a1.w*x1.w
         + a2.x*x2.x + a2.y*x2.y + a2.z*x2.z + a2.w*x2.w
         + a3.x*x3.x + a3.y*x3.y + a3.z*x3.z + a3.w*x3.w;
}

// Kernel 1: inv_norm[row] = 1 / max(||h_row||, 1e-12); one block per row, D=1024.
__global__ __launch_bounds__(256) void tcl_norm_kernel(const float* __restrict__ h,
                                                       float* __restrict__ inv_norm) {
    const int row = blockIdx.x;
    const float4* h4 = reinterpret_cast<const float4*>(h) + (size_t)row * 256;
    float4 v = h4[threadIdx.x];
    float ss = v.x*v.x + v.y*v.y + v.z*v.z + v.w*v.w;
    ss = wave_reduce_sum(ss);
    __shared__ float wsum[4];
    const int lane = threadIdx.x & 63, wid = threadIdx.x >> 6;
    if (lane == 0) wsum[wid] = ss;
    __syncthreads();
    if (threadIdx.x == 0) {
        float tot = wsum[0] + wsum[1] + wsum[2] + wsum[3];
        inv_norm[row] = 1.0f / fmaxf(sqrtf(tot), 1e-12f);
    }
}

// Kernel 2: one block handles (b, t0..t0+TM-1). 256 threads = 4 waves.
// Each wave streams s = t0+NM+wid, +4, ... ; computes TM dots per s against
// register-resident anchors; online logsumexp per (wave, tm); LDS combine.
__global__ __launch_bounds__(256) void tcl_loss_kernel(const float* __restrict__ h,
                                                       const float* __restrict__ inv_norm,
                                                       float* __restrict__ out,
                                                       int T, int Tv, float scale) {
    const int D4  = 256;                       // D/4 float4s per row
    const int nbt = (Tv + TM - 1) / TM;        // t-tiles per batch
    const int b   = blockIdx.x / nbt;
    const int t0  = (blockIdx.x - b * nbt) * TM;

    const float4* hb4 = reinterpret_cast<const float4*>(h) + (size_t)b * T * D4;
    const float*  inb = inv_norm + (size_t)b * T;

    const int lane = threadIdx.x & 63;
    const int wid  = threadIdx.x >> 6;

    // Anchor fragments in registers: anc[tm][j] = row(t0+tm), float4 at d4 = lane + 64*j.
    // (t0+tm <= 504+3 = 507 < T, always a valid row.)
    float4 anc[TM][4];
#pragma unroll
    for (int tm = 0; tm < TM; ++tm) {
        const float4* ar = hb4 + (size_t)(t0 + tm) * D4;
#pragma unroll
        for (int j = 0; j < 4; ++j) anc[tm][j] = ar[lane + 64*j];
    }
    float invt[TM];
#pragma unroll
    for (int tm = 0; tm < TM; ++tm) invt[tm] = inb[t0 + tm] * TEMP_INV;

    float m[TM], ssum[TM];
#pragma unroll
    for (int tm = 0; tm < TM; ++tm) { m[tm] = NEG_BIG; ssum[tm] = 0.f; }

    // Negatives: s in [t0+NM, T), strided across the 4 waves.
    for (int s = t0 + NMc + wid; s < T; s += 4) {
        const float4* hs = hb4 + (size_t)s * D4;
        float4 x0 = hs[lane], x1 = hs[lane + 64], x2 = hs[lane + 128], x3 = hs[lane + 192];
        float acc[TM];
#pragma unroll
        for (int tm = 0; tm < TM; ++tm)
            acc[tm] = dot16(anc[tm][0], anc[tm][1], anc[tm][2], anc[tm][3], x0, x1, x2, x3);
#pragma unroll
        for (int tm = 0; tm < TM; ++tm) acc[tm] = wave_reduce_sum(acc[tm]);

        const float invs = inb[s];
#pragma unroll
        for (int tm = 0; tm < TM; ++tm) {
            if (s >= t0 + tm + NMc) {               // wave-uniform predicate
                float score = acc[tm] * invt[tm] * invs;
                if (score > m[tm]) {
                    ssum[tm] = ssum[tm] * __expf(m[tm] - score) + 1.0f;
                    m[tm] = score;
                } else {
                    ssum[tm] += __expf(score - m[tm]);
                }
            }
        }
    }

    // Positives: wave `wid` handles t = t0 + wid (reload its anchor to keep
    // register indexing static — rule: no runtime-indexed register arrays).
    __shared__ float red_m[4][TM], red_s[4][TM], pos_sh[TM];
    {
        const int t = t0 + wid;
        const float4* ar = hb4 + (size_t)t * D4;
        float4 a0 = ar[lane], a1 = ar[lane + 64], a2 = ar[lane + 128], a3 = ar[lane + 192];
        const float invt_w = inb[t] * TEMP_INV;
        float pd = 0.f, cnt = 0.f;
#pragma unroll
        for (int oi = 0; oi < 4; ++oi) {
            const int o = (oi < 2) ? (oi - 2) : (oi - 1);   // -2,-1,1,2
            const int s = t + o;
            if (s >= 0 && s < T) {                           // wave-uniform
                const float4* hs = hb4 + (size_t)s * D4;
                float4 x0 = hs[lane], x1 = hs[lane + 64], x2 = hs[lane + 128], x3 = hs[lane + 192];
                float a = dot16(a0, a1, a2, a3, x0, x1, x2, x3);
                a = wave_reduce_sum(a);
                pd += a * inb[s];
                cnt += 1.f;
            }
        }
        const float pos_score = pd / cnt * invt_w;
        if (lane == 0) {
            pos_sh[wid] = pos_score;
#pragma unroll
            for (int tm = 0; tm < TM; ++tm) { red_m[wid][tm] = m[tm]; red_s[wid][tm] = ssum[tm]; }
        }
    }
    __syncthreads();

    if (threadIdx.x < TM) {
        const int tm = threadIdx.x;
        if (t0 + tm < Tv) {
            const float ps = pos_sh[tm];
            float M = ps;
#pragma unroll
            for (int w = 0; w < 4; ++w) M = fmaxf(M, red_m[w][tm]);
            float S = __expf(ps - M);
#pragma unroll
            for (int w = 0; w < 4; ++w) S += red_s[w][tm] * __expf(red_m[w][tm] - M);
            const float loss = __logf(S) + M - ps;
            atomicAdd(out, loss * scale);
        }
    }
}

extern "C" void kernel_launch(void* const* d_in, const int* in_sizes, int n_in,
                              void* d_out, int out_size, void* d_ws, size_t ws_size,
                              hipStream_t stream) {
    const float* h = (const float*)d_in[0];
    float* out = (float*)d_out;
    float* inv_norm = (float*)d_ws;            // B*T floats = 128 KB

    const int B = 64, T = 512;
    const int Tv = T - NMc - 1;                // 506
    const int nbt = (Tv + TM - 1) / TM;        // 127

    hipMemsetAsync(d_out, 0, (size_t)out_size * sizeof(float), stream);
    tcl_norm_kernel<<<B * T, 256, 0, stream>>>(h, inv_norm);
    tcl_loss_kernel<<<B * nbt, 256, 0, stream>>>(h, inv_norm, out, T, Tv,
                                                 1.0f / (float)(B * Tv));
}

// Round 2
// 693.344 us; speedup vs baseline: 1.6218x; 1.6218x over previous
//
#include <hip/hip_runtime.h>
#include <hip/hip_bf16.h>
#include <math.h>

// Problem constants (B=64, T=512, D=1024 from reference setup)
constexpr int   Bc       = 64;
constexpr int   Tc       = 512;
constexpr int   Dc       = 1024;
constexpr int   NMc      = 5;
constexpr int   TvC      = Tc - NMc - 1;   // 506
constexpr float TEMP_INV = 10.0f;
constexpr float NEG_BIG  = -1e30f;

using bf16x8 = __attribute__((ext_vector_type(8))) short;
using f32x4  = __attribute__((ext_vector_type(4))) float;

__device__ inline float bf2f(short s) {
    union { unsigned u; float f; } v;
    v.u = ((unsigned)(unsigned short)s) << 16;
    return v.f;
}
__device__ inline short f2bf(float f) {   // round-to-nearest-even
    unsigned u = __float_as_uint(f);
    unsigned r = (u + 0x7fffu + ((u >> 16) & 1u)) >> 16;
    return (short)r;
}
__device__ inline float wave_reduce_sum(float v) {
#pragma unroll
    for (int off = 32; off; off >>= 1) v += __shfl_xor(v, off);
    return v;
}

// ---------------------------------------------------------------------------
// Kernel 1: normalize each row, write bf16 feats to workspace.
// One block per row (B*T rows), 256 threads, float4 per thread.
__global__ __launch_bounds__(256) void tcl_prep(const float* __restrict__ h,
                                                short* __restrict__ fb) {
    const int row = blockIdx.x;
    const float4* h4 = reinterpret_cast<const float4*>(h) + (size_t)row * 256;
    float4 v = h4[threadIdx.x];
    float ss = v.x*v.x + v.y*v.y + v.z*v.z + v.w*v.w;
    ss = wave_reduce_sum(ss);
    __shared__ float wsum[4];
    __shared__ float inv_sh;
    const int lane = threadIdx.x & 63, wid = threadIdx.x >> 6;
    if (lane == 0) wsum[wid] = ss;
    __syncthreads();
    if (threadIdx.x == 0)
        inv_sh = 1.0f / fmaxf(sqrtf(wsum[0] + wsum[1] + wsum[2] + wsum[3]), 1e-12f);
    __syncthreads();
    const float inv = inv_sh;
    short4 o;
    o.x = f2bf(v.x * inv); o.y = f2bf(v.y * inv);
    o.z = f2bf(v.z * inv); o.w = f2bf(v.w * inv);
    reinterpret_cast<short4*>(fb + (size_t)row * Dc)[threadIdx.x] = o;
}

// ---------------------------------------------------------------------------
// Kernel 2: MFMA flash-style negative-score pass.
// Block = (b, t-tile of 64, s-parity half). 4 waves in 2x2 grid; each wave owns
// a 32x32 C sub-tile as 2x2 fragments of 16x16, K=1024 fully accumulated per
// 64-wide s-tile. Fixed-max logsumexp (scores in [-10,10] => reference max 10):
// S += exp(score-10), no running max / rescale. Partials atomicAdd into S_ws.
__global__ __launch_bounds__(256) void tcl_scores(const short* __restrict__ fb,
                                                  float* __restrict__ S_ws) {
    const int bx    = blockIdx.x;
    const int b     = bx >> 4;
    const int ti    = (bx >> 1) & 7;
    const int shalf = bx & 1;
    const int t0    = ti * 64;

    const short* f  = fb + (size_t)b * Tc * Dc;
    const int lane  = threadIdx.x & 63;
    const int wid   = threadIdx.x >> 6;
    const int wr    = wid >> 1, wc = wid & 1;

    const int koff  = (lane >> 4) * 8;
    const short* aptr0 = f + (size_t)(t0 + wr*32 + (lane & 15)) * Dc + koff;
    const short* aptr1 = aptr0 + 16 * Dc;

    float S0[4] = {0.f,0.f,0.f,0.f};   // rows i=0 (frag row r)
    float S1[4] = {0.f,0.f,0.f,0.f};   // rows i=1

    const int rowbase = t0 + wr*32 + (lane >> 4) * 4;   // global t of reg r=0, i=0

    for (int si = ti + shalf; si < 8; si += 2) {
        const int s0 = si * 64;
        const short* bptr0 = f + (size_t)(s0 + wc*32 + (lane & 15)) * Dc + koff;
        const short* bptr1 = bptr0 + 16 * Dc;

        f32x4 acc00{0.f,0.f,0.f,0.f}, acc01{0.f,0.f,0.f,0.f};
        f32x4 acc10{0.f,0.f,0.f,0.f}, acc11{0.f,0.f,0.f,0.f};
#pragma unroll
        for (int kk = 0; kk < 32; ++kk) {
            const int kb = kk * 32;
            bf16x8 a0 = *(const bf16x8*)(aptr0 + kb);
            bf16x8 a1 = *(const bf16x8*)(aptr1 + kb);
            bf16x8 b0 = *(const bf16x8*)(bptr0 + kb);
            bf16x8 b1 = *(const bf16x8*)(bptr1 + kb);
            acc00 = __builtin_amdgcn_mfma_f32_16x16x32_bf16(a0, b0, acc00, 0, 0, 0);
            acc01 = __builtin_amdgcn_mfma_f32_16x16x32_bf16(a0, b1, acc01, 0, 0, 0);
            acc10 = __builtin_amdgcn_mfma_f32_16x16x32_bf16(a1, b0, acc10, 0, 0, 0);
            acc11 = __builtin_amdgcn_mfma_f32_16x16x32_bf16(a1, b1, acc11, 0, 0, 0);
        }
        // C/D layout (16x16x32): col = lane&15, row = (lane>>4)*4 + reg.
        const int colbase = s0 + wc*32 + (lane & 15);
#pragma unroll
        for (int r = 0; r < 4; ++r) {
            const int ti0 = rowbase + r;        // global t for i=0
            const int ti1 = ti0 + 16;           // global t for i=1
            float sc;
            sc = acc00[r] * TEMP_INV; S0[r] += (colbase      >= ti0 + NMc) ? __expf(sc - 10.f) : 0.f;
            sc = acc01[r] * TEMP_INV; S0[r] += (colbase + 16 >= ti0 + NMc) ? __expf(sc - 10.f) : 0.f;
            sc = acc10[r] * TEMP_INV; S1[r] += (colbase      >= ti1 + NMc) ? __expf(sc - 10.f) : 0.f;
            sc = acc11[r] * TEMP_INV; S1[r] += (colbase + 16 >= ti1 + NMc) ? __expf(sc - 10.f) : 0.f;
        }
    }

    // Reduce Sigma-exp across the 16 lanes of each row group, combine col-halves.
    __shared__ float S_sh[2][64];
#pragma unroll
    for (int r = 0; r < 4; ++r) {
        float v0 = S0[r], v1 = S1[r];
#pragma unroll
        for (int off = 1; off < 16; off <<= 1) {
            v0 += __shfl_xor(v0, off);
            v1 += __shfl_xor(v1, off);
        }
        if ((lane & 15) == 0) {
            const int rl = wr*32 + (lane >> 4) * 4 + r;
            S_sh[wc][rl]      = v0;
            S_sh[wc][rl + 16] = v1;
        }
    }
    __syncthreads();
    if (threadIdx.x < 64) {
        const int t = t0 + threadIdx.x;
        if (t < TvC) {
            const float s = S_sh[0][threadIdx.x] + S_sh[1][threadIdx.x];
            atomicAdd(&S_ws[(size_t)b * Tc + t], s);
        }
    }
}

// ---------------------------------------------------------------------------
// Kernel 3: positives + combine. One wave per (b,t).
__global__ __launch_bounds__(256) void tcl_pos(const short* __restrict__ fb,
                                               const float* __restrict__ S_ws,
                                               float* __restrict__ out, float scale) {
    const int lane = threadIdx.x & 63;
    const int idx  = blockIdx.x * 4 + (threadIdx.x >> 6);
    if (idx >= Bc * TvC) return;                 // wave-uniform
    const int b = idx / TvC, t = idx - b * TvC;
    const short* f  = fb + (size_t)b * Tc * Dc;
    const short* ar = f + (size_t)t * Dc + lane * 16;
    bf16x8 a0 = *(const bf16x8*)ar;
    bf16x8 a1 = *(const bf16x8*)(ar + 8);
    float pd = 0.f, cnt = 0.f;
#pragma unroll
    for (int oi = 0; oi < 4; ++oi) {
        const int o = (oi < 2) ? (oi - 2) : (oi - 1);   // -2,-1,1,2
        const int s = t + o;
        if (s >= 0 && s < Tc) {                          // wave-uniform
            const short* xr = f + (size_t)s * Dc + lane * 16;
            bf16x8 x0 = *(const bf16x8*)xr;
            bf16x8 x1 = *(const bf16x8*)(xr + 8);
            float d = 0.f;
#pragma unroll
            for (int j = 0; j < 8; ++j)
                d += bf2f(a0[j]) * bf2f(x0[j]) + bf2f(a1[j]) * bf2f(x1[j]);
            pd += d; cnt += 1.f;
        }
    }
    pd = wave_reduce_sum(pd);
    if (lane == 0) {
        const float pos   = pd / cnt * TEMP_INV;
        const float total = __expf(pos - 10.f) + S_ws[(size_t)b * Tc + t];
        const float loss  = __logf(total) + 10.f - pos;
        atomicAdd(out, loss * scale);
    }
}

// ---------------------------------------------------------------------------
// Fallback (round-1 fp32 path) in case ws is too small for bf16 feats.
constexpr int TMF = 4;
__device__ inline float dot16(const float4 a0, const float4 a1, const float4 a2, const float4 a3,
                              const float4 x0, const float4 x1, const float4 x2, const float4 x3) {
    return a0.x*x0.x + a0.y*x0.y + a0.z*x0.z + a0.w*x0.w
         + a1.x*x1.x + a1.y*x1.y + a1.z*x1.z + a1.w*x1.w
         + a2.x*x2.x + a2.y*x2.y + a2.z*x2.z + a2.w*x2.w
         + a3.x*x3.x + a3.y*x3.y + a3.z*x3.z + a3.w*x3.w;
}
__global__ __launch_bounds__(256) void tcl_norm_kernel(const float* __restrict__ h,
                                                       float* __restrict__ inv_norm) {
    const int row = blockIdx.x;
    const float4* h4 = reinterpret_cast<const float4*>(h) + (size_t)row * 256;
    float4 v = h4[threadIdx.x];
    float ss = v.x*v.x + v.y*v.y + v.z*v.z + v.w*v.w;
    ss = wave_reduce_sum(ss);
    __shared__ float wsum[4];
    const int lane = threadIdx.x & 63, wid = threadIdx.x >> 6;
    if (lane == 0) wsum[wid] = ss;
    __syncthreads();
    if (threadIdx.x == 0)
        inv_norm[row] = 1.0f / fmaxf(sqrtf(wsum[0]+wsum[1]+wsum[2]+wsum[3]), 1e-12f);
}
__global__ __launch_bounds__(256) void tcl_loss_kernel(const float* __restrict__ h,
                                                       const float* __restrict__ inv_norm,
                                                       float* __restrict__ out,
                                                       int T, int Tv, float scale) {
    const int D4 = 256;
    const int nbt = (Tv + TMF - 1) / TMF;
    const int b  = blockIdx.x / nbt;
    const int t0 = (blockIdx.x - b * nbt) * TMF;
    const float4* hb4 = reinterpret_cast<const float4*>(h) + (size_t)b * T * D4;
    const float*  inb = inv_norm + (size_t)b * T;
    const int lane = threadIdx.x & 63, wid = threadIdx.x >> 6;
    float4 anc[TMF][4];
#pragma unroll
    for (int tm = 0; tm < TMF; ++tm) {
        const float4* ar = hb4 + (size_t)(t0 + tm) * D4;
#pragma unroll
        for (int j = 0; j < 4; ++j) anc[tm][j] = ar[lane + 64*j];
    }
    float invt[TMF];
#pragma unroll
    for (int tm = 0; tm < TMF; ++tm) invt[tm] = inb[t0 + tm] * TEMP_INV;
    float m[TMF], ssum[TMF];
#pragma unroll
    for (int tm = 0; tm < TMF; ++tm) { m[tm] = NEG_BIG; ssum[tm] = 0.f; }
    for (int s = t0 + NMc + wid; s < T; s += 4) {
        const float4* hs = hb4 + (size_t)s * D4;
        float4 x0 = hs[lane], x1 = hs[lane+64], x2 = hs[lane+128], x3 = hs[lane+192];
        float acc[TMF];
#pragma unroll
        for (int tm = 0; tm < TMF; ++tm)
            acc[tm] = dot16(anc[tm][0], anc[tm][1], anc[tm][2], anc[tm][3], x0, x1, x2, x3);
#pragma unroll
        for (int tm = 0; tm < TMF; ++tm) acc[tm] = wave_reduce_sum(acc[tm]);
        const float invs = inb[s];
#pragma unroll
        for (int tm = 0; tm < TMF; ++tm) {
            if (s >= t0 + tm + NMc) {
                float score = acc[tm] * invt[tm] * invs;
                if (score > m[tm]) { ssum[tm] = ssum[tm]*__expf(m[tm]-score) + 1.f; m[tm] = score; }
                else               { ssum[tm] += __expf(score - m[tm]); }
            }
        }
    }
    __shared__ float red_m[4][TMF], red_s[4][TMF], pos_sh[TMF];
    {
        const int t = t0 + wid;
        const float4* ar = hb4 + (size_t)t * D4;
        float4 a0 = ar[lane], a1 = ar[lane+64], a2 = ar[lane+128], a3 = ar[lane+192];
        const float invt_w = inb[t] * TEMP_INV;
        float pd = 0.f, cnt = 0.f;
#pragma unroll
        for (int oi = 0; oi < 4; ++oi) {
            const int o = (oi < 2) ? (oi - 2) : (oi - 1);
            const int s = t + o;
            if (s >= 0 && s < T) {
                const float4* hs = hb4 + (size_t)s * D4;
                float4 x0 = hs[lane], x1 = hs[lane+64], x2 = hs[lane+128], x3 = hs[lane+192];
                float a = dot16(a0,a1,a2,a3,x0,x1,x2,x3);
                a = wave_reduce_sum(a);
                pd += a * inb[s]; cnt += 1.f;
            }
        }
        const float pos_score = pd / cnt * invt_w;
        if (lane == 0) {
            pos_sh[wid] = pos_score;
#pragma unroll
            for (int tm = 0; tm < TMF; ++tm) { red_m[wid][tm] = m[tm]; red_s[wid][tm] = ssum[tm]; }
        }
    }
    __syncthreads();
    if (threadIdx.x < TMF) {
        const int tm = threadIdx.x;
        if (t0 + tm < Tv) {
            const float ps = pos_sh[tm];
            float M = ps;
#pragma unroll
            for (int w = 0; w < 4; ++w) M = fmaxf(M, red_m[w][tm]);
            float S = __expf(ps - M);
#pragma unroll
            for (int w = 0; w < 4; ++w) S += red_s[w][tm] * __expf(red_m[w][tm] - M);
            atomicAdd(out, (__logf(S) + M - ps) * scale);
        }
    }
}

// ---------------------------------------------------------------------------
extern "C" void kernel_launch(void* const* d_in, const int* in_sizes, int n_in,
                              void* d_out, int out_size, void* d_ws, size_t ws_size,
                              hipStream_t stream) {
    const float* h = (const float*)d_in[0];
    float* out = (float*)d_out;

    const size_t feats_bytes = (size_t)Bc * Tc * Dc * sizeof(short);   // 64 MiB
    const size_t sws_bytes   = (size_t)Bc * Tc * sizeof(float);        // 128 KiB
    const float  scale       = 1.0f / (float)(Bc * TvC);

    hipMemsetAsync(d_out, 0, (size_t)out_size * sizeof(float), stream);

    if (ws_size >= feats_bytes + sws_bytes) {
        short* fb   = (short*)d_ws;
        float* S_ws = (float*)((char*)d_ws + feats_bytes);
        hipMemsetAsync(S_ws, 0, sws_bytes, stream);
        tcl_prep<<<Bc * Tc, 256, 0, stream>>>(h, fb);
        tcl_scores<<<Bc * 8 * 2, 256, 0, stream>>>(fb, S_ws);
        const int nwave = Bc * TvC;
        tcl_pos<<<(nwave + 3) / 4, 256, 0, stream>>>(fb, S_ws, out, scale);
    } else {
        float* inv_norm = (float*)d_ws;   // 128 KiB
        const int nbt = (TvC + TMF - 1) / TMF;
        tcl_norm_kernel<<<Bc * Tc, 256, 0, stream>>>(h, inv_norm);
        tcl_loss_kernel<<<Bc * nbt, 256, 0, stream>>>(h, inv_norm, out, Tc, TvC, scale);
    }
}

// Round 3
// 161.331 us; speedup vs baseline: 6.9697x; 4.2977x over previous
//
#include <hip/hip_runtime.h>
#include <hip/hip_bf16.h>
#include <math.h>

// Problem constants (B=64, T=512, D=1024 from reference setup)
constexpr int   Bc       = 64;
constexpr int   Tc       = 512;
constexpr int   Dc       = 1024;
constexpr int   NMc      = 5;
constexpr int   TvC      = Tc - NMc - 1;   // 506
constexpr float TEMP_INV = 10.0f;

using bf16x8 = __attribute__((ext_vector_type(8))) short;
using f32x4  = __attribute__((ext_vector_type(4))) float;

__device__ inline float bf2f(short s) {
    union { unsigned u; float f; } v;
    v.u = ((unsigned)(unsigned short)s) << 16;
    return v.f;
}
__device__ inline short f2bf(float f) {   // round-to-nearest-even
    unsigned u = __float_as_uint(f);
    unsigned r = (u + 0x7fffu + ((u >> 16) & 1u)) >> 16;
    return (short)r;
}
__device__ inline float wave_reduce_sum(float v) {
#pragma unroll
    for (int off = 32; off; off >>= 1) v += __shfl_xor(v, off);
    return v;
}

// ---------------------------------------------------------------------------
// Kernel 1: normalize each row, write bf16 feats to workspace.
__global__ __launch_bounds__(256) void tcl_prep(const float* __restrict__ h,
                                                short* __restrict__ fb) {
    const int row = blockIdx.x;
    const float4* h4 = reinterpret_cast<const float4*>(h) + (size_t)row * 256;
    float4 v = h4[threadIdx.x];
    float ss = v.x*v.x + v.y*v.y + v.z*v.z + v.w*v.w;
    ss = wave_reduce_sum(ss);
    __shared__ float wsum[4];
    __shared__ float inv_sh;
    const int lane = threadIdx.x & 63, wid = threadIdx.x >> 6;
    if (lane == 0) wsum[wid] = ss;
    __syncthreads();
    if (threadIdx.x == 0)
        inv_sh = 1.0f / fmaxf(sqrtf(wsum[0] + wsum[1] + wsum[2] + wsum[3]), 1e-12f);
    __syncthreads();
    const float inv = inv_sh;
    short4 o;
    o.x = f2bf(v.x * inv); o.y = f2bf(v.y * inv);
    o.z = f2bf(v.z * inv); o.w = f2bf(v.w * inv);
    reinterpret_cast<short4*>(fb + (size_t)row * Dc)[threadIdx.x] = o;
}

// ---------------------------------------------------------------------------
// Kernel 2: MFMA negative-score pass, 128x128 tile jobs.
// Upper-triangular job list per batch: (ti,sj) 128-tiles with any s >= t+NM.
// 4 waves in 2x2; each wave computes a 64x64 C sub-tile as 4x4 fragments of
// 16x16x32 bf16 MFMA, K=1024 fully accumulated. Fixed-ref logsumexp: scores
// are 10*cos_sim in [-10,10], so S += exp(score-10) with constant max 10.
__device__ __constant__ unsigned char JOB_TI[10] = {0,0,0,0,1,1,1,2,2,3};
__device__ __constant__ unsigned char JOB_SJ[10] = {0,1,2,3,1,2,3,2,3,3};

__global__ __launch_bounds__(256) void tcl_scores(const short* __restrict__ fb,
                                                  float* __restrict__ S_ws) {
    // XCD-chunked swizzle: physical block p -> (b, job) such that each batch's
    // 10 jobs land on one XCD (p%8 constant). p in [0, 640).
    const int p  = blockIdx.x;
    const int b  = (p & 7) * 8 + ((p >> 3) / 10);
    const int j  = (p >> 3) % 10;
    const int t0 = (int)JOB_TI[j] * 128;
    const int s0 = (int)JOB_SJ[j] * 128;

    const short* f = fb + (size_t)b * Tc * Dc;
    const int lane = threadIdx.x & 63;
    const int wid  = threadIdx.x >> 6;
    const int wr   = wid >> 1, wc = wid & 1;

    const int r16  = lane & 15;          // row/col within fragment
    const int kg   = lane >> 4;          // k-group (0..3), 8 elems each
    const short* abase = f + (size_t)(t0 + wr*64 + r16) * Dc + kg * 8;
    const short* bbase = f + (size_t)(s0 + wc*64 + r16) * Dc + kg * 8;

    f32x4 acc[4][4];
#pragma unroll
    for (int fa = 0; fa < 4; ++fa)
#pragma unroll
        for (int fbj = 0; fbj < 4; ++fbj) acc[fa][fbj] = f32x4{0.f,0.f,0.f,0.f};

#pragma unroll 4
    for (int kk = 0; kk < 32; ++kk) {
        const int kb = kk * 32;
        bf16x8 av[4], bv[4];
#pragma unroll
        for (int q = 0; q < 4; ++q) {
            av[q] = *(const bf16x8*)(abase + (size_t)(q*16) * Dc + kb);
            bv[q] = *(const bf16x8*)(bbase + (size_t)(q*16) * Dc + kb);
        }
#pragma unroll
        for (int fa = 0; fa < 4; ++fa)
#pragma unroll
            for (int fbj = 0; fbj < 4; ++fbj)
                acc[fa][fbj] = __builtin_amdgcn_mfma_f32_16x16x32_bf16(av[fa], bv[fbj], acc[fa][fbj], 0, 0, 0);
    }

    // C/D layout: col = lane&15, row = (lane>>4)*4 + reg.
    // Sigma-exp per row; mask col >= row + NM.
    __shared__ float S_sh[2][128];
#pragma unroll
    for (int fa = 0; fa < 4; ++fa) {
#pragma unroll
        for (int r = 0; r < 4; ++r) {
            const int trow = t0 + wr*64 + fa*16 + kg*4 + r;
            float v = 0.f;
#pragma unroll
            for (int fbj = 0; fbj < 4; ++fbj) {
                const int col = s0 + wc*64 + fbj*16 + r16;
                const float sc = acc[fa][fbj][r] * TEMP_INV;
                v += (col >= trow + NMc) ? __expf(sc - 10.f) : 0.f;
            }
#pragma unroll
            for (int off = 1; off < 16; off <<= 1) v += __shfl_xor(v, off);
            if (r16 == 0) S_sh[wc][wr*64 + fa*16 + kg*4 + r] = v;
        }
    }
    __syncthreads();
    if (threadIdx.x < 128) {
        const int t = t0 + threadIdx.x;
        if (t < TvC) {
            const float s = S_sh[0][threadIdx.x] + S_sh[1][threadIdx.x];
            if (s != 0.f) atomicAdd(&S_ws[(size_t)b * Tc + t], s);
        }
    }
}

// ---------------------------------------------------------------------------
// Kernel 3: positives + combine. Block = (b, 64-t chunk); wave handles
// t = chunk*64 + wid + 4k. positives dot via dot(a, sum_o f[t+o]) -> ONE
// wave-reduce per t. Block-level LDS reduce -> ONE atomicAdd per block.
__global__ __launch_bounds__(256) void tcl_pos(const short* __restrict__ fb,
                                               const float* __restrict__ S_ws,
                                               float* __restrict__ out, float scale) {
    const int b     = blockIdx.x >> 3;
    const int base  = (blockIdx.x & 7) * 64;
    const int lane  = threadIdx.x & 63;
    const int wid   = threadIdx.x >> 6;
    const short* f  = fb + (size_t)b * Tc * Dc;

    float lsum = 0.f;   // meaningful on lane 0
    for (int lt = wid; lt < 64; lt += 4) {
        const int t = base + lt;
        if (t >= TvC) break;                    // wave-uniform
        const short* ar = f + (size_t)t * Dc + lane * 16;
        bf16x8 a0 = *(const bf16x8*)ar;
        bf16x8 a1 = *(const bf16x8*)(ar + 8);
        float xs[16];
#pragma unroll
        for (int q = 0; q < 16; ++q) xs[q] = 0.f;
        float cnt = 0.f;
#pragma unroll
        for (int oi = 0; oi < 4; ++oi) {
            const int o = (oi < 2) ? (oi - 2) : (oi - 1);   // -2,-1,1,2
            const int s = t + o;
            if (s >= 0 && s < Tc) {                          // wave-uniform
                const short* xr = f + (size_t)s * Dc + lane * 16;
                bf16x8 x0 = *(const bf16x8*)xr;
                bf16x8 x1 = *(const bf16x8*)(xr + 8);
#pragma unroll
                for (int q = 0; q < 8; ++q) { xs[q] += bf2f(x0[q]); xs[q+8] += bf2f(x1[q]); }
                cnt += 1.f;
            }
        }
        float d = 0.f;
#pragma unroll
        for (int q = 0; q < 8; ++q) d += bf2f(a0[q]) * xs[q] + bf2f(a1[q]) * xs[q+8];
        d = wave_reduce_sum(d);
        if (lane == 0) {
            const float pos   = d / cnt * TEMP_INV;
            const float total = __expf(pos - 10.f) + S_ws[(size_t)b * Tc + t];
            lsum += __logf(total) + 10.f - pos;
        }
    }
    __shared__ float wls[4];
    if (lane == 0) wls[wid] = lsum;
    __syncthreads();
    if (threadIdx.x == 0)
        atomicAdd(out, (wls[0] + wls[1] + wls[2] + wls[3]) * scale);
}

// ---------------------------------------------------------------------------
extern "C" void kernel_launch(void* const* d_in, const int* in_sizes, int n_in,
                              void* d_out, int out_size, void* d_ws, size_t ws_size,
                              hipStream_t stream) {
    const float* h = (const float*)d_in[0];
    float* out = (float*)d_out;

    const size_t feats_bytes = (size_t)Bc * Tc * Dc * sizeof(short);   // 64 MiB
    const size_t sws_bytes   = (size_t)Bc * Tc * sizeof(float);        // 128 KiB
    const float  scale       = 1.0f / (float)(Bc * TvC);

    short* fb   = (short*)d_ws;
    float* S_ws = (float*)((char*)d_ws + feats_bytes);

    hipMemsetAsync(d_out, 0, (size_t)out_size * sizeof(float), stream);
    hipMemsetAsync(S_ws, 0, sws_bytes, stream);
    tcl_prep<<<Bc * Tc, 256, 0, stream>>>(h, fb);
    tcl_scores<<<Bc * 10, 256, 0, stream>>>(fb, S_ws);
    tcl_pos<<<Bc * 8, 256, 0, stream>>>(fb, S_ws, out, scale);
    (void)ws_size; (void)in_sizes; (void)n_in; (void)out_size;
}

// Round 4
// 112.802 us; speedup vs baseline: 9.9682x; 1.4302x over previous
//
#include <hip/hip_runtime.h>
#include <hip/hip_bf16.h>
#include <math.h>

// Problem constants (B=64, T=512, D=1024 from reference setup)
constexpr int   Bc       = 64;
constexpr int   Tc       = 512;
constexpr int   Dc       = 1024;
constexpr int   NMc      = 5;
constexpr int   TvC      = Tc - NMc - 1;   // 506
constexpr float TEMP_INV = 10.0f;

using bf16x8 = __attribute__((ext_vector_type(8))) short;
using f32x4  = __attribute__((ext_vector_type(4))) float;

__device__ inline float bf2f(short s) {
    union { unsigned u; float f; } v;
    v.u = ((unsigned)(unsigned short)s) << 16;
    return v.f;
}
__device__ inline short f2bf(float f) {   // round-to-nearest-even
    unsigned u = __float_as_uint(f);
    unsigned r = (u + 0x7fffu + ((u >> 16) & 1u)) >> 16;
    return (short)r;
}
__device__ inline float wave_reduce_sum(float v) {
#pragma unroll
    for (int off = 32; off; off >>= 1) v += __shfl_xor(v, off);
    return v;
}

#define GLOAD16(gp, lp)                                                        \
    __builtin_amdgcn_global_load_lds(                                          \
        (const __attribute__((address_space(1))) void*)(gp),                   \
        (__attribute__((address_space(3))) void*)(lp), 16, 0, 0)

// ---------------------------------------------------------------------------
// Kernel 1: normalize each row, write bf16 feats to workspace.
__global__ __launch_bounds__(256) void tcl_prep(const float* __restrict__ h,
                                                short* __restrict__ fb) {
    const int row = blockIdx.x;
    const float4* h4 = reinterpret_cast<const float4*>(h) + (size_t)row * 256;
    float4 v = h4[threadIdx.x];
    float ss = v.x*v.x + v.y*v.y + v.z*v.z + v.w*v.w;
    ss = wave_reduce_sum(ss);
    __shared__ float wsum[4];
    __shared__ float inv_sh;
    const int lane = threadIdx.x & 63, wid = threadIdx.x >> 6;
    if (lane == 0) wsum[wid] = ss;
    __syncthreads();
    if (threadIdx.x == 0)
        inv_sh = 1.0f / fmaxf(sqrtf(wsum[0] + wsum[1] + wsum[2] + wsum[3]), 1e-12f);
    __syncthreads();
    const float inv = inv_sh;
    short4 o;
    o.x = f2bf(v.x * inv); o.y = f2bf(v.y * inv);
    o.z = f2bf(v.z * inv); o.w = f2bf(v.w * inv);
    reinterpret_cast<short4*>(fb + (size_t)row * Dc)[threadIdx.x] = o;
}

// ---------------------------------------------------------------------------
// Kernel 2: MFMA negative-score pass, m97-structure GEMM per 128x128 tile job.
// BK=64, 4 waves (2x2), wave = 64x64 C as 4x4 frags of 16x16x32 bf16.
// Staging: global_load_lds width=16, LINEAR LDS dest; XOR-swizzle st-style via
// pre-swizzled GLOBAL source (rule: both-sides-or-neither). LDS tile [128][64]
// bf16; byte' = byte ^ ((row&7)<<4) -> 2-way banks on ds_read_b128 (free).
// Fixed-ref logsumexp: scores are 10*cos in [-10,10] => S += exp(sc-10).
__device__ __constant__ unsigned char JOB_TI[10] = {0,0,0,0,1,1,1,2,2,3};
__device__ __constant__ unsigned char JOB_SJ[10] = {0,1,2,3,1,2,3,2,3,3};

__global__ __launch_bounds__(256) void tcl_scores(const short* __restrict__ fb,
                                                  float* __restrict__ S_ws) {
    // XCD-chunked swizzle: p%8 = XCD chunk; each batch's 10 jobs share an XCD.
    const int p  = blockIdx.x;
    const int b  = (p & 7) * 8 + ((p >> 3) / 10);
    const int j  = (p >> 3) % 10;
    const int t0 = (int)JOB_TI[j] * 128;
    const int s0 = (int)JOB_SJ[j] * 128;

    const short* f = fb + (size_t)b * Tc * Dc;
    const int lane = threadIdx.x & 63;
    const int wid  = threadIdx.x >> 6;
    const int wr   = wid >> 1, wc = wid & 1;

    __shared__ short Als[128 * 64];   // 16 KB, row stride 64 shorts (128 B)
    __shared__ short Bls[128 * 64];   // 16 KB

    // ---- staging addresses (per-lane global, linear LDS dest) ----
    // Each 1KB gload_lds instr: 8 rows x 128 B. lane l -> row sub=l>>3, chunk c8=l&7.
    // Source col chunk is XOR-permuted within the row: csw = (c8 ^ sub) * 8 shorts.
    const int sub = lane >> 3;
    const int c8  = lane & 7;
    const int csw = (c8 ^ sub) << 3;
    const short* gA[4]; const short* gB[4];
    short* lA[4]; short* lB[4];
#pragma unroll
    for (int i = 0; i < 4; ++i) {
        const int r = (wid * 4 + i) * 8 + sub;
        gA[i] = f + (size_t)(t0 + r) * Dc + csw;
        gB[i] = f + (size_t)(s0 + r) * Dc + csw;
        lA[i] = Als + (wid * 4 + i) * 512;    // 1024 B regions
        lB[i] = Bls + (wid * 4 + i) * 512;
    }

    // ---- fragment read offsets (shorts), swizzled to match ----
    const int r16 = lane & 15, kg = lane >> 4;
    int aoff[4][2], boff[4][2];
#pragma unroll
    for (int q = 0; q < 4; ++q)
#pragma unroll
        for (int ks = 0; ks < 2; ++ks) {
            const int ra = wr * 64 + q * 16 + r16;
            const int rb = wc * 64 + q * 16 + r16;
            const int cb = (ks * 64 + kg * 16) ^ ((r16 & 7) << 4);  // bytes
            aoff[q][ks] = ra * 64 + (cb >> 1);
            boff[q][ks] = rb * 64 + (cb >> 1);
        }

    f32x4 acc[4][4];
#pragma unroll
    for (int fa = 0; fa < 4; ++fa)
#pragma unroll
        for (int fbj = 0; fbj < 4; ++fbj) acc[fa][fbj] = f32x4{0.f, 0.f, 0.f, 0.f};

    // ---- K loop: 16 steps of BK=64, single-buffered, 2 barriers/step ----
    for (int kt = 0; kt < 16; ++kt) {
#pragma unroll
        for (int i = 0; i < 4; ++i) {
            GLOAD16(gA[i], lA[i]);
            GLOAD16(gB[i], lB[i]);
            gA[i] += 64; gB[i] += 64;
        }
        __syncthreads();   // drains vmcnt -> LDS tiles ready

        bf16x8 av[4][2], bv[4][2];
#pragma unroll
        for (int q = 0; q < 4; ++q)
#pragma unroll
            for (int ks = 0; ks < 2; ++ks) {
                av[q][ks] = *(const bf16x8*)(Als + aoff[q][ks]);
                bv[q][ks] = *(const bf16x8*)(Bls + boff[q][ks]);
            }
#pragma unroll
        for (int fa = 0; fa < 4; ++fa)
#pragma unroll
            for (int fbj = 0; fbj < 4; ++fbj)
#pragma unroll
                for (int ks = 0; ks < 2; ++ks)
                    acc[fa][fbj] = __builtin_amdgcn_mfma_f32_16x16x32_bf16(
                        av[fa][ks], bv[fbj][ks], acc[fa][fbj], 0, 0, 0);
        __syncthreads();   // all reads done before next stage overwrites
    }

    // ---- epilogue: mask, exp(sc-10), row-reduce, one atomic per t ----
    __shared__ float S_sh[2][128];
#pragma unroll
    for (int fa = 0; fa < 4; ++fa) {
#pragma unroll
        for (int r = 0; r < 4; ++r) {
            const int trow = t0 + wr * 64 + fa * 16 + kg * 4 + r;
            float v = 0.f;
#pragma unroll
            for (int fbj = 0; fbj < 4; ++fbj) {
                const int col = s0 + wc * 64 + fbj * 16 + r16;
                const float sc = acc[fa][fbj][r] * TEMP_INV;
                v += (col >= trow + NMc) ? __expf(sc - 10.f) : 0.f;
            }
#pragma unroll
            for (int off = 1; off < 16; off <<= 1) v += __shfl_xor(v, off);
            if (r16 == 0) S_sh[wc][wr * 64 + fa * 16 + kg * 4 + r] = v;
        }
    }
    __syncthreads();
    if (threadIdx.x < 128) {
        const int t = t0 + threadIdx.x;
        if (t < TvC) {
            const float s = S_sh[0][threadIdx.x] + S_sh[1][threadIdx.x];
            if (s != 0.f) atomicAdd(&S_ws[(size_t)b * Tc + t], s);
        }
    }
}

// ---------------------------------------------------------------------------
// Kernel 3: positives + combine. Block = (b, 64-t chunk); ONE atomic per block.
__global__ __launch_bounds__(256) void tcl_pos(const short* __restrict__ fb,
                                               const float* __restrict__ S_ws,
                                               float* __restrict__ out, float scale) {
    const int b     = blockIdx.x >> 3;
    const int base  = (blockIdx.x & 7) * 64;
    const int lane  = threadIdx.x & 63;
    const int wid   = threadIdx.x >> 6;
    const short* f  = fb + (size_t)b * Tc * Dc;

    float lsum = 0.f;   // meaningful on lane 0
    for (int lt = wid; lt < 64; lt += 4) {
        const int t = base + lt;
        if (t >= TvC) break;                    // wave-uniform
        const short* ar = f + (size_t)t * Dc + lane * 16;
        bf16x8 a0 = *(const bf16x8*)ar;
        bf16x8 a1 = *(const bf16x8*)(ar + 8);
        float xs[16];
#pragma unroll
        for (int q = 0; q < 16; ++q) xs[q] = 0.f;
        float cnt = 0.f;
#pragma unroll
        for (int oi = 0; oi < 4; ++oi) {
            const int o = (oi < 2) ? (oi - 2) : (oi - 1);   // -2,-1,1,2
            const int s = t + o;
            if (s >= 0 && s < Tc) {                          // wave-uniform
                const short* xr = f + (size_t)s * Dc + lane * 16;
                bf16x8 x0 = *(const bf16x8*)xr;
                bf16x8 x1 = *(const bf16x8*)(xr + 8);
#pragma unroll
                for (int q = 0; q < 8; ++q) { xs[q] += bf2f(x0[q]); xs[q+8] += bf2f(x1[q]); }
                cnt += 1.f;
            }
        }
        float d = 0.f;
#pragma unroll
        for (int q = 0; q < 8; ++q) d += bf2f(a0[q]) * xs[q] + bf2f(a1[q]) * xs[q+8];
        d = wave_reduce_sum(d);
        if (lane == 0) {
            const float pos   = d / cnt * TEMP_INV;
            const float total = __expf(pos - 10.f) + S_ws[(size_t)b * Tc + t];
            lsum += __logf(total) + 10.f - pos;
        }
    }
    __shared__ float wls[4];
    if (lane == 0) wls[wid] = lsum;
    __syncthreads();
    if (threadIdx.x == 0)
        atomicAdd(out, (wls[0] + wls[1] + wls[2] + wls[3]) * scale);
}

// ---------------------------------------------------------------------------
extern "C" void kernel_launch(void* const* d_in, const int* in_sizes, int n_in,
                              void* d_out, int out_size, void* d_ws, size_t ws_size,
                              hipStream_t stream) {
    const float* h = (const float*)d_in[0];
    float* out = (float*)d_out;

    const size_t feats_bytes = (size_t)Bc * Tc * Dc * sizeof(short);   // 64 MiB
    const size_t sws_bytes   = (size_t)Bc * Tc * sizeof(float);        // 128 KiB
    const float  scale       = 1.0f / (float)(Bc * TvC);

    short* fb   = (short*)d_ws;
    float* S_ws = (float*)((char*)d_ws + feats_bytes);

    hipMemsetAsync(d_out, 0, (size_t)out_size * sizeof(float), stream);
    hipMemsetAsync(S_ws, 0, sws_bytes, stream);
    tcl_prep<<<Bc * Tc, 256, 0, stream>>>(h, fb);
    tcl_scores<<<Bc * 10, 256, 0, stream>>>(fb, S_ws);
    tcl_pos<<<Bc * 8, 256, 0, stream>>>(fb, S_ws, out, scale);
    (void)ws_size; (void)in_sizes; (void)n_in; (void)out_size;
}

// Round 5
// 106.940 us; speedup vs baseline: 10.5147x; 1.0548x over previous
//
#include <hip/hip_runtime.h>
#include <hip/hip_bf16.h>
#include <math.h>

// Problem constants (B=64, T=512, D=1024 from reference setup)
constexpr int   Bc       = 64;
constexpr int   Tc       = 512;
constexpr int   Dc       = 1024;
constexpr int   NMc      = 5;
constexpr int   TvC      = Tc - NMc - 1;   // 506
constexpr float TEMP_INV = 10.0f;

using bf16x8 = __attribute__((ext_vector_type(8))) short;
using f32x4  = __attribute__((ext_vector_type(4))) float;

__device__ inline float bf2f(short s) {
    union { unsigned u; float f; } v;
    v.u = ((unsigned)(unsigned short)s) << 16;
    return v.f;
}
__device__ inline short f2bf(float f) {   // round-to-nearest-even
    unsigned u = __float_as_uint(f);
    unsigned r = (u + 0x7fffu + ((u >> 16) & 1u)) >> 16;
    return (short)r;
}
__device__ inline float wave_reduce_sum(float v) {
#pragma unroll
    for (int off = 32; off; off >>= 1) v += __shfl_xor(v, off);
    return v;
}

#define GLOAD16(gp, lp)                                                        \
    __builtin_amdgcn_global_load_lds(                                          \
        (const __attribute__((address_space(1))) void*)(gp),                   \
        (__attribute__((address_space(3))) void*)(lp), 16, 0, 0)

// ---------------------------------------------------------------------------
// Kernel 1: normalize rows -> bf16 feats. Wave-per-row, no LDS, no barriers.
// Also zeroes the output accumulator (block 0): stream-ordered before tcl_pos.
__global__ __launch_bounds__(256) void tcl_prep(const float* __restrict__ h,
                                                short* __restrict__ fb,
                                                float* __restrict__ out) {
    if (blockIdx.x == 0 && threadIdx.x == 0) *out = 0.f;
    const int row  = blockIdx.x * 4 + (threadIdx.x >> 6);
    const int lane = threadIdx.x & 63;
    const float4* h4 = reinterpret_cast<const float4*>(h) + (size_t)row * 256 + lane;
    float4 v[4];
    float ss = 0.f;
#pragma unroll
    for (int i = 0; i < 4; ++i) {
        v[i] = h4[i * 64];
        ss += v[i].x*v[i].x + v[i].y*v[i].y + v[i].z*v[i].z + v[i].w*v[i].w;
    }
    ss = wave_reduce_sum(ss);                       // all lanes hold total
    const float inv = 1.0f / fmaxf(sqrtf(ss), 1e-12f);
    short4* o4 = reinterpret_cast<short4*>(fb + (size_t)row * Dc) + lane;
#pragma unroll
    for (int i = 0; i < 4; ++i) {
        short4 o;
        o.x = f2bf(v[i].x * inv); o.y = f2bf(v[i].y * inv);
        o.z = f2bf(v[i].z * inv); o.w = f2bf(v[i].w * inv);
        o4[i * 64] = o;
    }
}

// ---------------------------------------------------------------------------
// Kernel 2: MFMA negative-score pass, m97-structure GEMM per 128x128 tile job.
// BK=64, 4 waves (2x2), wave = 64x64 C as 4x4 frags of 16x16x32 bf16.
// Staging: global_load_lds width=16, LINEAR LDS dest; XOR-swizzle via
// pre-swizzled GLOBAL source (both-sides-or-neither). LDS tile [128][64] bf16;
// byte' = byte ^ ((row&7)<<4) -> conflict-free-ish ds_read_b128.
// Fixed-ref logsumexp: scores are 10*cos in [-10,10] => S += exp(sc-10).
// Output: S_part[b][sj][t] written by the UNIQUE job (ti=t>>7, sj) -> no init.
__device__ __constant__ unsigned char JOB_TI[10] = {0,0,0,0,1,1,1,2,2,3};
__device__ __constant__ unsigned char JOB_SJ[10] = {0,1,2,3,1,2,3,2,3,3};

__global__ __launch_bounds__(256) void tcl_scores(const short* __restrict__ fb,
                                                  float* __restrict__ S_part) {
    // XCD-chunked swizzle: p%8 = XCD chunk; each batch's 10 jobs share an XCD.
    const int p  = blockIdx.x;
    const int b  = (p & 7) * 8 + ((p >> 3) / 10);
    const int j  = (p >> 3) % 10;
    const int t0 = (int)JOB_TI[j] * 128;
    const int sj = (int)JOB_SJ[j];
    const int s0 = sj * 128;

    const short* f = fb + (size_t)b * Tc * Dc;
    const int lane = threadIdx.x & 63;
    const int wid  = threadIdx.x >> 6;
    const int wr   = wid >> 1, wc = wid & 1;

    __shared__ short Als[128 * 64];   // 16 KB, row stride 64 shorts (128 B)
    __shared__ short Bls[128 * 64];   // 16 KB

    // ---- staging addresses (per-lane global, linear LDS dest) ----
    // Each 1KB gload_lds instr: 8 rows x 128 B. lane l -> row sub=l>>3, chunk c8=l&7.
    // Source col chunk XOR-permuted within the row: csw = (c8 ^ sub) * 8 shorts.
    const int sub = lane >> 3;
    const int c8  = lane & 7;
    const int csw = (c8 ^ sub) << 3;
    const short* gA[4]; const short* gB[4];
    short* lA[4]; short* lB[4];
#pragma unroll
    for (int i = 0; i < 4; ++i) {
        const int r = (wid * 4 + i) * 8 + sub;
        gA[i] = f + (size_t)(t0 + r) * Dc + csw;
        gB[i] = f + (size_t)(s0 + r) * Dc + csw;
        lA[i] = Als + (wid * 4 + i) * 512;    // 1024 B regions
        lB[i] = Bls + (wid * 4 + i) * 512;
    }

    // ---- fragment read offsets (shorts), swizzled to match ----
    const int r16 = lane & 15, kg = lane >> 4;
    int aoff[4][2], boff[4][2];
#pragma unroll
    for (int q = 0; q < 4; ++q)
#pragma unroll
        for (int ks = 0; ks < 2; ++ks) {
            const int ra = wr * 64 + q * 16 + r16;
            const int rb = wc * 64 + q * 16 + r16;
            const int cb = (ks * 64 + kg * 16) ^ ((r16 & 7) << 4);  // bytes
            aoff[q][ks] = ra * 64 + (cb >> 1);
            boff[q][ks] = rb * 64 + (cb >> 1);
        }

    f32x4 acc[4][4];
#pragma unroll
    for (int fa = 0; fa < 4; ++fa)
#pragma unroll
        for (int fbj = 0; fbj < 4; ++fbj) acc[fa][fbj] = f32x4{0.f, 0.f, 0.f, 0.f};

    // ---- K loop: 16 steps of BK=64, single-buffered, 2 barriers/step ----
    for (int kt = 0; kt < 16; ++kt) {
#pragma unroll
        for (int i = 0; i < 4; ++i) {
            GLOAD16(gA[i], lA[i]);
            GLOAD16(gB[i], lB[i]);
            gA[i] += 64; gB[i] += 64;
        }
        __syncthreads();   // drains vmcnt -> LDS tiles ready

        bf16x8 av[4][2], bv[4][2];
#pragma unroll
        for (int q = 0; q < 4; ++q)
#pragma unroll
            for (int ks = 0; ks < 2; ++ks) {
                av[q][ks] = *(const bf16x8*)(Als + aoff[q][ks]);
                bv[q][ks] = *(const bf16x8*)(Bls + boff[q][ks]);
            }
#pragma unroll
        for (int fa = 0; fa < 4; ++fa)
#pragma unroll
            for (int fbj = 0; fbj < 4; ++fbj)
#pragma unroll
                for (int ks = 0; ks < 2; ++ks)
                    acc[fa][fbj] = __builtin_amdgcn_mfma_f32_16x16x32_bf16(
                        av[fa][ks], bv[fbj][ks], acc[fa][fbj], 0, 0, 0);
        __syncthreads();   // all reads done before next stage overwrites
    }

    // ---- epilogue: mask, exp(sc-10), row-reduce, plain store to S_part ----
    __shared__ float S_sh[2][128];
#pragma unroll
    for (int fa = 0; fa < 4; ++fa) {
#pragma unroll
        for (int r = 0; r < 4; ++r) {
            const int trow = t0 + wr * 64 + fa * 16 + kg * 4 + r;
            float v = 0.f;
#pragma unroll
            for (int fbj = 0; fbj < 4; ++fbj) {
                const int col = s0 + wc * 64 + fbj * 16 + r16;
                const float sc = acc[fa][fbj][r] * TEMP_INV;
                v += (col >= trow + NMc) ? __expf(sc - 10.f) : 0.f;
            }
#pragma unroll
            for (int off = 1; off < 16; off <<= 1) v += __shfl_xor(v, off);
            if (r16 == 0) S_sh[wc][wr * 64 + fa * 16 + kg * 4 + r] = v;
        }
    }
    __syncthreads();
    if (threadIdx.x < 128) {
        const int t = t0 + threadIdx.x;
        S_part[((size_t)b * 4 + sj) * Tc + t] = S_sh[0][threadIdx.x] + S_sh[1][threadIdx.x];
    }
}

// ---------------------------------------------------------------------------
// Kernel 3: positives + combine. Block = (b, 64-t chunk); ONE atomic per block.
__global__ __launch_bounds__(256) void tcl_pos(const short* __restrict__ fb,
                                               const float* __restrict__ S_part,
                                               float* __restrict__ out, float scale) {
    const int b     = blockIdx.x >> 3;
    const int base  = (blockIdx.x & 7) * 64;
    const int ti    = base >> 7;                 // 128-chunk index (block-uniform)
    const int lane  = threadIdx.x & 63;
    const int wid   = threadIdx.x >> 6;
    const short* f  = fb + (size_t)b * Tc * Dc;

    float lsum = 0.f;   // meaningful on lane 0
    for (int lt = wid; lt < 64; lt += 4) {
        const int t = base + lt;
        if (t >= TvC) break;                    // wave-uniform
        const short* ar = f + (size_t)t * Dc + lane * 16;
        bf16x8 a0 = *(const bf16x8*)ar;
        bf16x8 a1 = *(const bf16x8*)(ar + 8);
        float xs[16];
#pragma unroll
        for (int q = 0; q < 16; ++q) xs[q] = 0.f;
        float cnt = 0.f;
#pragma unroll
        for (int oi = 0; oi < 4; ++oi) {
            const int o = (oi < 2) ? (oi - 2) : (oi - 1);   // -2,-1,1,2
            const int s = t + o;
            if (s >= 0 && s < Tc) {                          // wave-uniform
                const short* xr = f + (size_t)s * Dc + lane * 16;
                bf16x8 x0 = *(const bf16x8*)xr;
                bf16x8 x1 = *(const bf16x8*)(xr + 8);
#pragma unroll
                for (int q = 0; q < 8; ++q) { xs[q] += bf2f(x0[q]); xs[q+8] += bf2f(x1[q]); }
                cnt += 1.f;
            }
        }
        float d = 0.f;
#pragma unroll
        for (int q = 0; q < 8; ++q) d += bf2f(a0[q]) * xs[q] + bf2f(a1[q]) * xs[q+8];
        d = wave_reduce_sum(d);
        if (lane == 0) {
            float S = 0.f;
            for (int sj = ti; sj < 4; ++sj)                 // block-uniform bound
                S += S_part[((size_t)b * 4 + sj) * Tc + t];
            const float pos   = d / cnt * TEMP_INV;
            const float total = __expf(pos - 10.f) + S;
            lsum += __logf(total) + 10.f - pos;
        }
    }
    __shared__ float wls[4];
    if (lane == 0) wls[wid] = lsum;
    __syncthreads();
    if (threadIdx.x == 0)
        atomicAdd(out, (wls[0] + wls[1] + wls[2] + wls[3]) * scale);
}

// ---------------------------------------------------------------------------
extern "C" void kernel_launch(void* const* d_in, const int* in_sizes, int n_in,
                              void* d_out, int out_size, void* d_ws, size_t ws_size,
                              hipStream_t stream) {
    const float* h = (const float*)d_in[0];
    float* out = (float*)d_out;

    const size_t feats_bytes = (size_t)Bc * Tc * Dc * sizeof(short);   // 64 MiB
    const float  scale       = 1.0f / (float)(Bc * TvC);

    short* fb     = (short*)d_ws;
    float* S_part = (float*)((char*)d_ws + feats_bytes);   // 64*4*512 floats = 512 KB

    tcl_prep<<<Bc * Tc / 4, 256, 0, stream>>>(h, fb, out);
    tcl_scores<<<Bc * 10, 256, 0, stream>>>(fb, S_part);
    tcl_pos<<<Bc * 8, 256, 0, stream>>>(fb, S_part, out, scale);
    (void)ws_size; (void)in_sizes; (void)n_in; (void)out_size;
}

// Round 6
// 85.540 us; speedup vs baseline: 13.1452x; 1.2502x over previous
//
#include <hip/hip_runtime.h>
#include <hip/hip_bf16.h>
#include <math.h>

// Problem constants (B=64, T=512, D=1024 from reference setup)
constexpr int   Bc       = 64;
constexpr int   Tc       = 512;
constexpr int   Dc       = 1024;
constexpr int   NMc      = 5;
constexpr int   TvC      = Tc - NMc - 1;   // 506
constexpr float TEMP_INV = 10.0f;

using bf16x8 = __attribute__((ext_vector_type(8))) short;
using f32x4  = __attribute__((ext_vector_type(4))) float;

__device__ inline short f2bf(float f) {   // round-to-nearest-even
    unsigned u = __float_as_uint(f);
    unsigned r = (u + 0x7fffu + ((u >> 16) & 1u)) >> 16;
    return (short)r;
}
__device__ inline float wave_reduce_sum(float v) {
#pragma unroll
    for (int off = 32; off; off >>= 1) v += __shfl_xor(v, off);
    return v;
}

#define GLOAD16(gp, lp)                                                        \
    __builtin_amdgcn_global_load_lds(                                          \
        (const __attribute__((address_space(1))) void*)(gp),                   \
        (__attribute__((address_space(3))) void*)(lp), 16, 0, 0)

// ---------------------------------------------------------------------------
// Kernel 1: normalize rows -> bf16 feats. Wave-per-row, no LDS, no barriers.
// Also zeroes the output accumulator (block 0): stream-ordered before combine.
__global__ __launch_bounds__(256) void tcl_prep(const float* __restrict__ h,
                                                short* __restrict__ fb,
                                                float* __restrict__ out) {
    if (blockIdx.x == 0 && threadIdx.x == 0) *out = 0.f;
    const int row  = blockIdx.x * 4 + (threadIdx.x >> 6);
    const int lane = threadIdx.x & 63;
    const float4* h4 = reinterpret_cast<const float4*>(h) + (size_t)row * 256 + lane;
    float4 v[4];
    float ss = 0.f;
#pragma unroll
    for (int i = 0; i < 4; ++i) {
        v[i] = h4[i * 64];
        ss += v[i].x*v[i].x + v[i].y*v[i].y + v[i].z*v[i].z + v[i].w*v[i].w;
    }
    ss = wave_reduce_sum(ss);                       // all lanes hold total
    const float inv = 1.0f / fmaxf(sqrtf(ss), 1e-12f);
    short4* o4 = reinterpret_cast<short4*>(fb + (size_t)row * Dc) + lane;
#pragma unroll
    for (int i = 0; i < 4; ++i) {
        short4 o;
        o.x = f2bf(v[i].x * inv); o.y = f2bf(v[i].y * inv);
        o.z = f2bf(v[i].z * inv); o.w = f2bf(v[i].w * inv);
        o4[i * 64] = o;
    }
}

// ---------------------------------------------------------------------------
// Kernel 2: MFMA negative-score pass + fused positive extraction.
// m97-structure GEMM per 128x128 tile job: BK=64, 4 waves (2x2), wave = 64x64 C
// as 4x4 frags of 16x16x32 bf16. global_load_lds width=16 with linear LDS dest
// + XOR-swizzled GLOBAL source; ds_read offsets XOR-matched.
// Fixed-ref logsumexp: scores are 10*cos in [-10,10] => S += exp(sc-10).
// S_part[b][sj][t]: write-once by unique job (t>>7, sj). Positives: each pair
// (t, t+o), |o|<=2, lives in exactly one job's acc — diagonal jobs harvest
// in-tile pairs (pos_d), super-diagonal jobs harvest boundary pairs (pos_x:
// rows t0+126/127 row-side, cols s0/s0+1 col-side). cnt is analytic.
__device__ __constant__ unsigned char JOB_TI[10] = {0,0,0,0,1,1,1,2,2,3};
__device__ __constant__ unsigned char JOB_SJ[10] = {0,1,2,3,1,2,3,2,3,3};

__global__ __launch_bounds__(256) void tcl_scores(const short* __restrict__ fb,
                                                  float* __restrict__ S_part,
                                                  float* __restrict__ pos_d,
                                                  float* __restrict__ pos_x) {
    // XCD-chunked swizzle: p%8 = XCD chunk; each batch's 10 jobs share an XCD.
    const int p  = blockIdx.x;
    const int b  = (p & 7) * 8 + ((p >> 3) / 10);
    const int j  = (p >> 3) % 10;
    const int ti = (int)JOB_TI[j];
    const int sj = (int)JOB_SJ[j];
    const int t0 = ti * 128;
    const int s0 = sj * 128;
    const bool is_diag  = (sj == ti);
    const bool is_super = (sj == ti + 1);

    const short* f = fb + (size_t)b * Tc * Dc;
    const int lane = threadIdx.x & 63;
    const int wid  = threadIdx.x >> 6;
    const int wr   = wid >> 1, wc = wid & 1;

    __shared__ short Als[128 * 64];   // 16 KB, row stride 64 shorts (128 B)
    __shared__ short Bls[128 * 64];   // 16 KB

    // ---- staging addresses (per-lane global, linear LDS dest) ----
    const int sub = lane >> 3;
    const int c8  = lane & 7;
    const int csw = (c8 ^ sub) << 3;
    const short* gA[4]; const short* gB[4];
    short* lA[4]; short* lB[4];
#pragma unroll
    for (int i = 0; i < 4; ++i) {
        const int r = (wid * 4 + i) * 8 + sub;
        gA[i] = f + (size_t)(t0 + r) * Dc + csw;
        gB[i] = f + (size_t)(s0 + r) * Dc + csw;
        lA[i] = Als + (wid * 4 + i) * 512;    // 1024 B regions
        lB[i] = Bls + (wid * 4 + i) * 512;
    }

    // ---- fragment read offsets (shorts), swizzled to match ----
    const int r16 = lane & 15, kg = lane >> 4;
    int aoff[4][2], boff[4][2];
#pragma unroll
    for (int q = 0; q < 4; ++q)
#pragma unroll
        for (int ks = 0; ks < 2; ++ks) {
            const int ra = wr * 64 + q * 16 + r16;
            const int rb = wc * 64 + q * 16 + r16;
            const int cb = (ks * 64 + kg * 16) ^ ((r16 & 7) << 4);  // bytes
            aoff[q][ks] = ra * 64 + (cb >> 1);
            boff[q][ks] = rb * 64 + (cb >> 1);
        }

    f32x4 acc[4][4];
#pragma unroll
    for (int fa = 0; fa < 4; ++fa)
#pragma unroll
        for (int fbj = 0; fbj < 4; ++fbj) acc[fa][fbj] = f32x4{0.f, 0.f, 0.f, 0.f};

    // ---- K loop: 16 steps of BK=64, single-buffered, 2 barriers/step ----
    for (int kt = 0; kt < 16; ++kt) {
#pragma unroll
        for (int i = 0; i < 4; ++i) {
            GLOAD16(gA[i], lA[i]);
            GLOAD16(gB[i], lB[i]);
            gA[i] += 64; gB[i] += 64;
        }
        __syncthreads();   // drains vmcnt -> LDS tiles ready

        bf16x8 av[4][2], bv[4][2];
#pragma unroll
        for (int q = 0; q < 4; ++q)
#pragma unroll
            for (int ks = 0; ks < 2; ++ks) {
                av[q][ks] = *(const bf16x8*)(Als + aoff[q][ks]);
                bv[q][ks] = *(const bf16x8*)(Bls + boff[q][ks]);
            }
#pragma unroll
        for (int fa = 0; fa < 4; ++fa)
#pragma unroll
            for (int fbj = 0; fbj < 4; ++fbj)
#pragma unroll
                for (int ks = 0; ks < 2; ++ks)
                    acc[fa][fbj] = __builtin_amdgcn_mfma_f32_16x16x32_bf16(
                        av[fa][ks], bv[fbj][ks], acc[fa][fbj], 0, 0, 0);
        __syncthreads();   // all reads done before next stage overwrites
    }

    // ---- epilogue: exp-sum (masked) + positive row-side harvest ----
    __shared__ float S_sh[2][128];
    __shared__ float P_sh[2][128];
#pragma unroll
    for (int fa = 0; fa < 4; ++fa) {
#pragma unroll
        for (int r = 0; r < 4; ++r) {
            const int trow = t0 + wr * 64 + fa * 16 + kg * 4 + r;
            float v = 0.f, pv = 0.f;
#pragma unroll
            for (int fbj = 0; fbj < 4; ++fbj) {
                const int col = s0 + wc * 64 + fbj * 16 + r16;
                const float sc = acc[fa][fbj][r] * TEMP_INV;
                v += (col >= trow + NMc) ? __expf(sc - 10.f) : 0.f;
                const int dd = col - trow;
                pv += (dd * dd == 1 || dd * dd == 4) ? sc : 0.f;
            }
#pragma unroll
            for (int off = 1; off < 16; off <<= 1) {
                v  += __shfl_xor(v, off);
                pv += __shfl_xor(pv, off);
            }
            if (r16 == 0) {
                const int rl = wr * 64 + fa * 16 + kg * 4 + r;
                S_sh[wc][rl] = v;
                P_sh[wc][rl] = pv;
            }
        }
    }

    // ---- col-side positive harvest (super-diagonal jobs only) ----
    // Pairs (u, v): u = t0+126/127 (rows), v = s0/s0+1 (cols). Value feeds
    // pos[v] (its -1/-2 neighbor). Only wave (wr=1,wc=0), fbj=0 can hold them.
    if (is_super && wr == 1 && wc == 0) {
        float cv = 0.f;
        const int c = s0 + r16;
#pragma unroll
        for (int fa = 0; fa < 4; ++fa)
#pragma unroll
            for (int r = 0; r < 4; ++r) {
                const int trow = t0 + 64 + fa * 16 + kg * 4 + r;
                const int dd = c - trow;
                cv += (dd == 1 || dd == 2) ? acc[fa][0][r] * TEMP_INV : 0.f;
            }
        cv += __shfl_xor(cv, 16);
        cv += __shfl_xor(cv, 32);
        if (kg == 0 && r16 < 2) pos_x[(size_t)b * Tc + c] = cv;
    }

    __syncthreads();
    if (threadIdx.x < 128) {
        const int t = t0 + threadIdx.x;
        S_part[((size_t)b * 4 + sj) * Tc + t] = S_sh[0][threadIdx.x] + S_sh[1][threadIdx.x];
        const float pr = P_sh[0][threadIdx.x] + P_sh[1][threadIdx.x];
        if (is_diag)
            pos_d[(size_t)b * Tc + t] = pr;
        if (is_super && threadIdx.x >= 126)        // rows t0+126, t0+127
            pos_x[(size_t)b * Tc + t] = pr;
    }
}

// ---------------------------------------------------------------------------
// Kernel 3: trivial combine. One block per batch; reads S_part slices + pos
// tables, closes the logsumexp, block-reduce, ONE atomicAdd per block.
__global__ __launch_bounds__(256) void tcl_combine(const float* __restrict__ S_part,
                                                   const float* __restrict__ pos_d,
                                                   const float* __restrict__ pos_x,
                                                   float* __restrict__ out, float scale) {
    const int b = blockIdx.x;
    float lsum = 0.f;
    for (int t = threadIdx.x; t < TvC; t += 256) {
        const int ti = t >> 7, tl = t & 127;
        float S = 0.f;
        for (int sj = ti; sj < 4; ++sj) S += S_part[((size_t)b * 4 + sj) * Tc + t];
        float praw = pos_d[(size_t)b * Tc + t];
        if ((tl >= 126 && ti < 3) || (tl <= 1 && ti > 0))
            praw += pos_x[(size_t)b * Tc + t];
        const float cnt = (t == 0) ? 2.f : (t == 1) ? 3.f : 4.f;
        const float pos = praw / cnt;
        lsum += __logf(__expf(pos - 10.f) + S) + 10.f - pos;
    }
    lsum = wave_reduce_sum(lsum);
    __shared__ float wls[4];
    const int lane = threadIdx.x & 63, wid = threadIdx.x >> 6;
    if (lane == 0) wls[wid] = lsum;
    __syncthreads();
    if (threadIdx.x == 0)
        atomicAdd(out, (wls[0] + wls[1] + wls[2] + wls[3]) * scale);
}

// ---------------------------------------------------------------------------
extern "C" void kernel_launch(void* const* d_in, const int* in_sizes, int n_in,
                              void* d_out, int out_size, void* d_ws, size_t ws_size,
                              hipStream_t stream) {
    const float* h = (const float*)d_in[0];
    float* out = (float*)d_out;

    const size_t feats_bytes = (size_t)Bc * Tc * Dc * sizeof(short);   // 64 MiB
    const size_t spart_bytes = (size_t)Bc * 4 * Tc * sizeof(float);    // 512 KiB
    const size_t posd_bytes  = (size_t)Bc * Tc * sizeof(float);        // 128 KiB
    const float  scale       = 1.0f / (float)(Bc * TvC);

    short* fb     = (short*)d_ws;
    float* S_part = (float*)((char*)d_ws + feats_bytes);
    float* pos_d  = (float*)((char*)d_ws + feats_bytes + spart_bytes);
    float* pos_x  = (float*)((char*)d_ws + feats_bytes + spart_bytes + posd_bytes);

    tcl_prep<<<Bc * Tc / 4, 256, 0, stream>>>(h, fb, out);
    tcl_scores<<<Bc * 10, 256, 0, stream>>>(fb, S_part, pos_d, pos_x);
    tcl_combine<<<Bc, 256, 0, stream>>>(S_part, pos_d, pos_x, out, scale);
    (void)ws_size; (void)in_sizes; (void)n_in; (void)out_size;
}

// Round 7
// 69.960 us; speedup vs baseline: 16.0725x; 1.2227x over previous
//
#include <hip/hip_runtime.h>
#include <hip/hip_bf16.h>
#include <math.h>

// Problem constants (B=64, T=512, D=1024 from reference setup)
constexpr int   Bc       = 64;
constexpr int   Tc       = 512;
constexpr int   Dc       = 1024;
constexpr int   NMc      = 5;
constexpr int   TvC      = Tc - NMc - 1;   // 506
constexpr float TEMP_INV = 10.0f;

using bf16x8 = __attribute__((ext_vector_type(8))) short;
using f32x4  = __attribute__((ext_vector_type(4))) float;

__device__ inline short f2bf(float f) {   // round-to-nearest-even
    unsigned u = __float_as_uint(f);
    unsigned r = (u + 0x7fffu + ((u >> 16) & 1u)) >> 16;
    return (short)r;
}
__device__ inline float wave_reduce_sum(float v) {
#pragma unroll
    for (int off = 32; off; off >>= 1) v += __shfl_xor(v, off);
    return v;
}

#define GLOAD16(gp, lp)                                                        \
    __builtin_amdgcn_global_load_lds(                                          \
        (const __attribute__((address_space(1))) void*)(gp),                   \
        (__attribute__((address_space(3))) void*)(lp), 16, 0, 0)

// ---------------------------------------------------------------------------
// Kernel 1: normalize rows -> bf16 feats. Wave-per-row, no LDS, no barriers.
// Also zeroes the output accumulator (block 0): stream-ordered before combine.
__global__ __launch_bounds__(256) void tcl_prep(const float* __restrict__ h,
                                                short* __restrict__ fb,
                                                float* __restrict__ out) {
    if (blockIdx.x == 0 && threadIdx.x == 0) *out = 0.f;
    const int row  = blockIdx.x * 4 + (threadIdx.x >> 6);
    const int lane = threadIdx.x & 63;
    const float4* h4 = reinterpret_cast<const float4*>(h) + (size_t)row * 256 + lane;
    float4 v[4];
    float ss = 0.f;
#pragma unroll
    for (int i = 0; i < 4; ++i) {
        v[i] = h4[i * 64];
        ss += v[i].x*v[i].x + v[i].y*v[i].y + v[i].z*v[i].z + v[i].w*v[i].w;
    }
    ss = wave_reduce_sum(ss);                       // all lanes hold total
    const float inv = 1.0f / fmaxf(sqrtf(ss), 1e-12f);
    short4* o4 = reinterpret_cast<short4*>(fb + (size_t)row * Dc) + lane;
#pragma unroll
    for (int i = 0; i < 4; ++i) {
        short4 o;
        o.x = f2bf(v[i].x * inv); o.y = f2bf(v[i].y * inv);
        o.z = f2bf(v[i].z * inv); o.w = f2bf(v[i].w * inv);
        o4[i * 64] = o;
    }
}

// ---------------------------------------------------------------------------
// Kernel 2: MFMA negative-score pass + fused positive extraction.
// 64(t) x 128(s) tile jobs, 20 per batch -> 1280 blocks (5/CU, uniform cost).
// BK=64, 4 waves (2x2); wave = 32x64 C as 2x4 frags of 16x16x32 bf16.
// global_load_lds width=16, linear LDS dest + XOR-swizzled GLOBAL source;
// ds_read offsets XOR-matched (both-sides-or-neither rule).
// Fixed-ref logsumexp: scores are 10*cos in [-10,10] => S += exp(sc-10).
// S_part[b][sj][t]: write-once (two jobs per sj cover disjoint 64-row halves).
// Positives: diagonal jobs ti in {2sj, 2sj+1} harvest in-segment pairs
// (pos_d); x-jobs (ti == 2sj-1) harvest boundary pairs (pos_x): rows
// t0+62/63 row-side, cols s0/s0+1 col-side. cnt is analytic in combine.
__device__ __constant__ unsigned char JOB_TI[20] =
    {0,1, 0,1,2,3, 0,1,2,3,4,5, 0,1,2,3,4,5,6,7};
__device__ __constant__ unsigned char JOB_SJ[20] =
    {0,0, 1,1,1,1, 2,2,2,2,2,2, 3,3,3,3,3,3,3,3};

__global__ __launch_bounds__(256) void tcl_scores(const short* __restrict__ fb,
                                                  float* __restrict__ S_part,
                                                  float* __restrict__ pos_d,
                                                  float* __restrict__ pos_x) {
    // XCD-chunked swizzle: p%8 = XCD chunk; each batch's 20 jobs share an XCD.
    const int p  = blockIdx.x;
    const int b  = (p & 7) * 8 + ((p >> 3) / 20);
    const int j  = (p >> 3) % 20;
    const int ti = (int)JOB_TI[j];
    const int sj = (int)JOB_SJ[j];
    const int t0 = ti * 64;
    const int s0 = sj * 128;
    const bool is_diag = (ti == 2 * sj) || (ti == 2 * sj + 1);
    const bool is_x    = (ti == 2 * sj - 1);

    const short* f = fb + (size_t)b * Tc * Dc;
    const int lane = threadIdx.x & 63;
    const int wid  = threadIdx.x >> 6;
    const int wr   = wid >> 1, wc = wid & 1;

    __shared__ short Als[64 * 64];    //  8 KB, row stride 64 shorts (128 B)
    __shared__ short Bls[128 * 64];   // 16 KB

    // ---- staging addresses (per-lane global, linear LDS dest) ----
    // Each 1KB gload_lds instr covers 8 rows x 128 B. lane l -> row sub=l>>3,
    // col chunk c8=l&7, source chunk XOR-permuted: csw = (c8 ^ sub) * 8 shorts.
    const int sub = lane >> 3;
    const int c8  = lane & 7;
    const int csw = (c8 ^ sub) << 3;
    const short* gA[2]; const short* gB[4];
    short* lA[2]; short* lB[4];
#pragma unroll
    for (int i = 0; i < 2; ++i) {
        const int ri = wid * 2 + i;               // 0..7
        gA[i] = f + (size_t)(t0 + ri * 8 + sub) * Dc + csw;
        lA[i] = Als + ri * 512;                   // 1024 B regions
    }
#pragma unroll
    for (int i = 0; i < 4; ++i) {
        const int ri = wid * 4 + i;               // 0..15
        gB[i] = f + (size_t)(s0 + ri * 8 + sub) * Dc + csw;
        lB[i] = Bls + ri * 512;
    }

    // ---- fragment read offsets (shorts), swizzled to match ----
    const int r16 = lane & 15, kg = lane >> 4;
    int aoff[2][2], boff[4][2];
#pragma unroll
    for (int ks = 0; ks < 2; ++ks) {
        const int cb = (ks * 64 + kg * 16) ^ ((r16 & 7) << 4);  // bytes
#pragma unroll
        for (int q = 0; q < 2; ++q)
            aoff[q][ks] = (wr * 32 + q * 16 + r16) * 64 + (cb >> 1);
#pragma unroll
        for (int q = 0; q < 4; ++q)
            boff[q][ks] = (wc * 64 + q * 16 + r16) * 64 + (cb >> 1);
    }

    f32x4 acc[2][4];
#pragma unroll
    for (int fa = 0; fa < 2; ++fa)
#pragma unroll
        for (int fbj = 0; fbj < 4; ++fbj) acc[fa][fbj] = f32x4{0.f, 0.f, 0.f, 0.f};

    // ---- K loop: 16 steps of BK=64, single-buffered, 2 barriers/step ----
    for (int kt = 0; kt < 16; ++kt) {
#pragma unroll
        for (int i = 0; i < 2; ++i) { GLOAD16(gA[i], lA[i]); gA[i] += 64; }
#pragma unroll
        for (int i = 0; i < 4; ++i) { GLOAD16(gB[i], lB[i]); gB[i] += 64; }
        __syncthreads();   // drains vmcnt -> LDS tiles ready

        bf16x8 av[2][2], bv[4][2];
#pragma unroll
        for (int ks = 0; ks < 2; ++ks) {
#pragma unroll
            for (int q = 0; q < 2; ++q) av[q][ks] = *(const bf16x8*)(Als + aoff[q][ks]);
#pragma unroll
            for (int q = 0; q < 4; ++q) bv[q][ks] = *(const bf16x8*)(Bls + boff[q][ks]);
        }
#pragma unroll
        for (int fa = 0; fa < 2; ++fa)
#pragma unroll
            for (int fbj = 0; fbj < 4; ++fbj)
#pragma unroll
                for (int ks = 0; ks < 2; ++ks)
                    acc[fa][fbj] = __builtin_amdgcn_mfma_f32_16x16x32_bf16(
                        av[fa][ks], bv[fbj][ks], acc[fa][fbj], 0, 0, 0);
        __syncthreads();   // all reads done before next stage overwrites
    }

    // ---- epilogue: exp-sum (masked) + positive row-side harvest ----
    __shared__ float S_sh[2][64];
    __shared__ float P_sh[2][64];
#pragma unroll
    for (int fa = 0; fa < 2; ++fa) {
#pragma unroll
        for (int r = 0; r < 4; ++r) {
            const int trow = t0 + wr * 32 + fa * 16 + kg * 4 + r;
            float v = 0.f, pv = 0.f;
#pragma unroll
            for (int fbj = 0; fbj < 4; ++fbj) {
                const int col = s0 + wc * 64 + fbj * 16 + r16;
                const float sc = acc[fa][fbj][r] * TEMP_INV;
                v += (col >= trow + NMc) ? __expf(sc - 10.f) : 0.f;
                const int dd = col - trow;
                pv += (dd * dd == 1 || dd * dd == 4) ? sc : 0.f;
            }
#pragma unroll
            for (int off = 1; off < 16; off <<= 1) {
                v  += __shfl_xor(v, off);
                pv += __shfl_xor(pv, off);
            }
            if (r16 == 0) {
                const int rl = wr * 32 + fa * 16 + kg * 4 + r;
                S_sh[wc][rl] = v;
                P_sh[wc][rl] = pv;
            }
        }
    }

    // ---- col-side positive harvest (x-jobs only) ----
    // Pairs (u, v): u = t0+62/63 (rows), v = s0/s0+1 (cols); value = sc(u,v)
    // feeds pos[v]. Rows 62/63 live in wave wr=1; cols s0/s0+1 in wc=0, fbj=0.
    if (is_x && wr == 1 && wc == 0) {
        float cv = 0.f;
        const int c = s0 + r16;
#pragma unroll
        for (int fa = 0; fa < 2; ++fa)
#pragma unroll
            for (int r = 0; r < 4; ++r) {
                const int trow = t0 + 32 + fa * 16 + kg * 4 + r;
                const int dd = c - trow;
                cv += (dd == 1 || dd == 2) ? acc[fa][0][r] * TEMP_INV : 0.f;
            }
        cv += __shfl_xor(cv, 16);
        cv += __shfl_xor(cv, 32);
        if (kg == 0 && r16 < 2) pos_x[(size_t)b * Tc + c] = cv;
    }

    __syncthreads();
    if (threadIdx.x < 64) {
        const int t = t0 + threadIdx.x;
        S_part[((size_t)b * 4 + sj) * Tc + t] = S_sh[0][threadIdx.x] + S_sh[1][threadIdx.x];
        const float pr = P_sh[0][threadIdx.x] + P_sh[1][threadIdx.x];
        if (is_diag)
            pos_d[(size_t)b * Tc + t] = pr;
        if (is_x && threadIdx.x >= 62)             // rows t0+62, t0+63
            pos_x[(size_t)b * Tc + t] = pr;
    }
}

// ---------------------------------------------------------------------------
// Kernel 3: trivial combine. One block per batch; reads S_part slices + pos
// tables, closes the logsumexp, block-reduce, ONE atomicAdd per block.
__global__ __launch_bounds__(256) void tcl_combine(const float* __restrict__ S_part,
                                                   const float* __restrict__ pos_d,
                                                   const float* __restrict__ pos_x,
                                                   float* __restrict__ out, float scale) {
    const int b = blockIdx.x;
    float lsum = 0.f;
    for (int t = threadIdx.x; t < TvC; t += 256) {
        const int ti = t >> 7, tl = t & 127;
        float S = 0.f;
        for (int sj = ti; sj < 4; ++sj) S += S_part[((size_t)b * 4 + sj) * Tc + t];
        float praw = pos_d[(size_t)b * Tc + t];
        if ((tl >= 126 && ti < 3) || (tl <= 1 && ti > 0))
            praw += pos_x[(size_t)b * Tc + t];
        const float cnt = (t == 0) ? 2.f : (t == 1) ? 3.f : 4.f;
        const float pos = praw / cnt;
        lsum += __logf(__expf(pos - 10.f) + S) + 10.f - pos;
    }
    lsum = wave_reduce_sum(lsum);
    __shared__ float wls[4];
    const int lane = threadIdx.x & 63, wid = threadIdx.x >> 6;
    if (lane == 0) wls[wid] = lsum;
    __syncthreads();
    if (threadIdx.x == 0)
        atomicAdd(out, (wls[0] + wls[1] + wls[2] + wls[3]) * scale);
}

// ---------------------------------------------------------------------------
extern "C" void kernel_launch(void* const* d_in, const int* in_sizes, int n_in,
                              void* d_out, int out_size, void* d_ws, size_t ws_size,
                              hipStream_t stream) {
    const float* h = (const float*)d_in[0];
    float* out = (float*)d_out;

    const size_t feats_bytes = (size_t)Bc * Tc * Dc * sizeof(short);   // 64 MiB
    const size_t spart_bytes = (size_t)Bc * 4 * Tc * sizeof(float);    // 512 KiB
    const size_t posd_bytes  = (size_t)Bc * Tc * sizeof(float);        // 128 KiB
    const float  scale       = 1.0f / (float)(Bc * TvC);

    short* fb     = (short*)d_ws;
    float* S_part = (float*)((char*)d_ws + feats_bytes);
    float* pos_d  = (float*)((char*)d_ws + feats_bytes + spart_bytes);
    float* pos_x  = (float*)((char*)d_ws + feats_bytes + spart_bytes + posd_bytes);

    tcl_prep<<<Bc * Tc / 4, 256, 0, stream>>>(h, fb, out);
    tcl_scores<<<Bc * 20, 256, 0, stream>>>(fb, S_part, pos_d, pos_x);
    tcl_combine<<<Bc, 256, 0, stream>>>(S_part, pos_d, pos_x, out, scale);
    (void)ws_size; (void)in_sizes; (void)n_in; (void)out_size;
}